// Round 4
// baseline (16846.303 us; speedup 1.0000x reference)
//
#include <hip/hip_runtime.h>
#include <hip/hip_cooperative_groups.h>
#include <math.h>

typedef unsigned int u32x4 __attribute__((ext_vector_type(4)));

constexpr int T = 4096;   // SEQ_LEN
constexpr int R = 2048;   // RES_SIZE
constexpr int J = 128;    // INPUT_SIZE
constexpr float ONE_MINUS_LEAK = 0.1f;
constexpr float LEAK = 0.9f;
constexpr float INV_SQRT_R = 0.022097086912079608f;  // 1/sqrt(2048)

constexpr int NWG = 256;  // one WG per CU

// ---------------- Kernel A: proj[t][r] = input[t] . W_in[r] + bias[r] -> d_out
__global__ __launch_bounds__(256) void esn_proj_kernel(
    const float* __restrict__ U, const float* __restrict__ Win,
    const float* __restrict__ bias, float* __restrict__ out)
{
    __shared__ float As[16][129];
    __shared__ float Bs[16][129];
    const int tb = blockIdx.x * 16;
    const int rb = blockIdx.y * 16;
    const int tid = threadIdx.x;

    for (int i = tid; i < 16 * J; i += 256) {
        int r = i >> 7, c = i & 127;
        As[r][c] = U[(size_t)(tb + r) * J + c];
        Bs[r][c] = Win[(size_t)(rb + r) * J + c];
    }
    __syncthreads();

    const int ti = tid >> 4;
    const int rj = tid & 15;
    float acc = 0.f;
#pragma unroll
    for (int k = 0; k < J; ++k) acc = fmaf(As[ti][k], Bs[rj][k], acc);
    out[(size_t)(tb + ti) * R + (rb + rj)] = acc + bias[rb + rj];
}

// ---------------- Kernel B: persistent recurrence, data-is-the-flag protocol
// 256 WGs x 512 threads; WG w owns rows [8w,8w+8), wave v owns row 8w+v.
// slots[2][R]: 8B words, lo32 = f32 bits, hi32 = tag (step index of the state).
// Producer: ONE relaxed agent-scope 8B store publishes value+validity.
// Consumer poll: 2x global_load_dwordx4 sc0 sc1 in flight under ONE waitcnt
// -> one round-trip per sweep (R3's atomic loads serialized 4 round-trips).
__global__ __launch_bounds__(512, 2) void esn_recur_kernel(
    const float* __restrict__ Wres, float* __restrict__ out,
    unsigned long long* __restrict__ slots /* [2][R] */)
{
    const int wg   = blockIdx.x;
    const int tid  = threadIdx.x;
    const int wave = tid >> 6;
    const int lane = tid & 63;
    const int row  = wg * 8 + wave;

    // Row weights in registers (coalesced: 64 lanes x f32 per k)
    float w[32];
    {
        const float* wr = Wres + (size_t)row * R + lane;
#pragma unroll
        for (int k = 0; k < 32; ++k) w[k] = wr[k * 64];
    }

    __shared__ float xs[2][R];
    float xold = 0.f;   // this row's previous state (used by lane 0)

    for (int t = 0; t < T; ++t) {
        // Prefetch input projection early; latency hides under the poll.
        float proj = 0.f;
        if (lane == 0) proj = out[(size_t)t * R + row];

        // Poll x^{(t)}: this thread owns slots {2tid,2tid+1} and {1024+2tid,+1}.
        const unsigned long long* src = slots + (size_t)(t & 1) * R;
        const unsigned long long* p0  = src + 2 * tid;
        const unsigned long long* p1  = src + 1024 + 2 * tid;
        const unsigned want = (unsigned)t;
        u32x4 v0, v1;
        while (true) {
            asm volatile(
                "global_load_dwordx4 %0, %2, off sc0 sc1\n\t"
                "global_load_dwordx4 %1, %3, off sc0 sc1\n\t"
                "s_waitcnt vmcnt(0)"
                : "=&v"(v0), "=&v"(v1)
                : "v"(p0), "v"(p1)
                : "memory");
            if (v0[1] == want && v0[3] == want &&
                v1[1] == want && v1[3] == want) break;
        }
        float* xb = xs[t & 1];
        xb[2 * tid]        = __uint_as_float(v0[0]);
        xb[2 * tid + 1]    = __uint_as_float(v0[2]);
        xb[2 * tid + 1024] = __uint_as_float(v1[0]);
        xb[2 * tid + 1025] = __uint_as_float(v1[2]);
        __syncthreads();   // the only barrier per step: stage -> dot join

        // Row dot product: 32 conflict-free LDS reads, 4 FMA chains.
        float a0 = 0.f, a1 = 0.f, a2 = 0.f, a3 = 0.f;
        const float* x = xs[t & 1];
#pragma unroll
        for (int k = 0; k < 8; ++k) {
            a0 = fmaf(w[4 * k + 0], x[(4 * k + 0) * 64 + lane], a0);
            a1 = fmaf(w[4 * k + 1], x[(4 * k + 1) * 64 + lane], a1);
            a2 = fmaf(w[4 * k + 2], x[(4 * k + 2) * 64 + lane], a2);
            a3 = fmaf(w[4 * k + 3], x[(4 * k + 3) * 64 + lane], a3);
        }
        float acc = (a0 + a1) + (a2 + a3);
#pragma unroll
        for (int off = 32; off > 0; off >>= 1)
            acc += __shfl_xor(acc, off);

        if (lane == 0) {
            float pre  = acc + proj;          // RES_SCALE = INPUT_SCALE = 1
            float xnew = ONE_MINUS_LEAK * xold + LEAK * erff(pre) * INV_SQRT_R;
            xold = xnew;
            // Publish FIRST (critical path), then the states output.
            unsigned long long packed =
                ((unsigned long long)(unsigned)(t + 1) << 32) |
                (unsigned long long)__float_as_uint(xnew);
            __hip_atomic_store(
                (unsigned long long*)&slots[(size_t)((t + 1) & 1) * R + row],
                packed, __ATOMIC_RELAXED, __HIP_MEMORY_SCOPE_AGENT);
            out[(size_t)t * R + row] = xnew;
        }
    }
}

extern "C" void kernel_launch(void* const* d_in, const int* in_sizes, int n_in,
                              void* d_out, int out_size, void* d_ws, size_t ws_size,
                              hipStream_t stream) {
    const float* U    = (const float*)d_in[0];  // (4096,128)
    const float* Win  = (const float*)d_in[1];  // (2048,128)
    const float* Wres = (const float*)d_in[2];  // (2048,2048)
    const float* bias = (const float*)d_in[3];  // (2048,)
    float* out = (float*)d_out;                 // (4096,2048)
    unsigned long long* slots = (unsigned long long*)d_ws;  // [2][R]

    // tag 0 / value 0 everywhere == valid x^0 = 0 for buf[0]; graph-replay safe.
    hipMemsetAsync(d_ws, 0, 2 * R * sizeof(unsigned long long), stream);

    dim3 pgrid(T / 16, R / 16);
    esn_proj_kernel<<<pgrid, dim3(256), 0, stream>>>(U, Win, bias, out);

    void* args[] = { (void*)&Wres, (void*)&out, (void*)&slots };
    hipLaunchCooperativeKernel((const void*)esn_recur_kernel,
                               dim3(NWG), dim3(512), args, 0, stream);
}

// Round 5
// 14621.638 us; speedup vs baseline: 1.1521x; 1.1521x over previous
//
#include <hip/hip_runtime.h>
#include <hip/hip_cooperative_groups.h>
#include <math.h>

typedef unsigned int u32x4 __attribute__((ext_vector_type(4)));

constexpr int T = 4096;   // SEQ_LEN
constexpr int R = 2048;   // RES_SIZE
constexpr int J = 128;    // INPUT_SIZE
constexpr float ONE_MINUS_LEAK = 0.1f;
constexpr float LEAK = 0.9f;
constexpr float INV_SQRT_R = 0.022097086912079608f;  // 1/sqrt(2048)

constexpr int NWG  = 256;  // one WG per CU
constexpr int NREP = 8;    // slot-array replicas (disjoint L3 regions)

// ---------------- Kernel A: proj[t][r] = input[t] . W_in[r] + bias[r] -> d_out
__global__ __launch_bounds__(256) void esn_proj_kernel(
    const float* __restrict__ U, const float* __restrict__ Win,
    const float* __restrict__ bias, float* __restrict__ out)
{
    __shared__ float As[16][129];
    __shared__ float Bs[16][129];
    const int tb = blockIdx.x * 16;
    const int rb = blockIdx.y * 16;
    const int tid = threadIdx.x;

    for (int i = tid; i < 16 * J; i += 256) {
        int r = i >> 7, c = i & 127;
        As[r][c] = U[(size_t)(tb + r) * J + c];
        Bs[r][c] = Win[(size_t)(rb + r) * J + c];
    }
    __syncthreads();

    const int ti = tid >> 4;
    const int rj = tid & 15;
    float acc = 0.f;
#pragma unroll
    for (int k = 0; k < J; ++k) acc = fmaf(As[ti][k], Bs[rj][k], acc);
    out[(size_t)(tb + ti) * R + (rb + rj)] = acc + bias[rb + rj];
}

// ---------------- Kernel B: persistent recurrence, replicated data-is-the-flag
// 256 WGs x 512 threads; WG w owns rows [8w,8w+8), wave v owns row 8w+v.
// slots[NREP][2][R]: 8B words, lo32 = f32 bits, hi32 = tag (step index).
// Producer lane0 publishes its row to ALL NREP regions (8 stores in flight).
// Each WG polls ONLY region (wg & 7) -> per-region poll traffic is 1/8 of
// R4's, and regions land on different L3 slices (32 KB apart) -> contention
// (the R4 limiter: 4 MB/sweep into one 16 KB region) drops ~8x.
__global__ __launch_bounds__(512, 2) void esn_recur_kernel(
    const float* __restrict__ Wres, float* __restrict__ out,
    unsigned long long* __restrict__ slots /* [NREP][2][R] */)
{
    const int wg   = blockIdx.x;
    const int tid  = threadIdx.x;
    const int wave = tid >> 6;
    const int lane = tid & 63;
    const int row  = wg * 8 + wave;
    const int grp  = wg & (NREP - 1);

    // Row weights in registers (coalesced: 64 lanes x f32 per k)
    float w[32];
    {
        const float* wr = Wres + (size_t)row * R + lane;
#pragma unroll
        for (int k = 0; k < 32; ++k) w[k] = wr[k * 64];
    }

    __shared__ float xs[2][R];
    float xold = 0.f;   // this row's previous state (used by lane 0)

    for (int t = 0; t < T; ++t) {
        // Prefetch input projection early; latency hides under the poll.
        float proj = 0.f;
        if (lane == 0) proj = out[(size_t)t * R + row];

        // Poll x^{(t)} in OUR replica region: thread owns slots
        // {2tid, 2tid+1} and {1024+2tid, 1024+2tid+1}.
        const unsigned long long* src =
            slots + ((size_t)(grp * 2 + (t & 1))) * R;
        const unsigned long long* p0 = src + 2 * tid;
        const unsigned long long* p1 = src + 1024 + 2 * tid;
        const unsigned want = (unsigned)t;
        u32x4 v0, v1;
        while (true) {
            asm volatile(
                "global_load_dwordx4 %0, %2, off sc0 sc1\n\t"
                "global_load_dwordx4 %1, %3, off sc0 sc1\n\t"
                "s_waitcnt vmcnt(0)"
                : "=&v"(v0), "=&v"(v1)
                : "v"(p0), "v"(p1)
                : "memory");
            if (v0[1] == want && v0[3] == want &&
                v1[1] == want && v1[3] == want) break;
        }
        float* xb = xs[t & 1];
        xb[2 * tid]        = __uint_as_float(v0[0]);
        xb[2 * tid + 1]    = __uint_as_float(v0[2]);
        xb[2 * tid + 1024] = __uint_as_float(v1[0]);
        xb[2 * tid + 1025] = __uint_as_float(v1[2]);
        __syncthreads();   // the only barrier per step: stage -> dot join

        // Row dot product: 32 conflict-free LDS reads, 4 FMA chains.
        float a0 = 0.f, a1 = 0.f, a2 = 0.f, a3 = 0.f;
        const float* x = xs[t & 1];
#pragma unroll
        for (int k = 0; k < 8; ++k) {
            a0 = fmaf(w[4 * k + 0], x[(4 * k + 0) * 64 + lane], a0);
            a1 = fmaf(w[4 * k + 1], x[(4 * k + 1) * 64 + lane], a1);
            a2 = fmaf(w[4 * k + 2], x[(4 * k + 2) * 64 + lane], a2);
            a3 = fmaf(w[4 * k + 3], x[(4 * k + 3) * 64 + lane], a3);
        }
        float acc = (a0 + a1) + (a2 + a3);
#pragma unroll
        for (int off = 32; off > 0; off >>= 1)
            acc += __shfl_xor(acc, off);

        if (lane == 0) {
            float pre  = acc + proj;          // RES_SCALE = INPUT_SCALE = 1
            float xnew = ONE_MINUS_LEAK * xold + LEAK * erff(pre) * INV_SQRT_R;
            xold = xnew;
            // Publish to all replicas FIRST (critical path): 8 independent
            // 8B sc0sc1 stores, all in flight. Then the states output.
            unsigned long long packed =
                ((unsigned long long)(unsigned)(t + 1) << 32) |
                (unsigned long long)__float_as_uint(xnew);
            const int nb = (t + 1) & 1;
#pragma unroll
            for (int g = 0; g < NREP; ++g)
                __hip_atomic_store(
                    &slots[((size_t)(g * 2 + nb)) * R + row], packed,
                    __ATOMIC_RELAXED, __HIP_MEMORY_SCOPE_AGENT);
            out[(size_t)t * R + row] = xnew;
        }
    }
}

extern "C" void kernel_launch(void* const* d_in, const int* in_sizes, int n_in,
                              void* d_out, int out_size, void* d_ws, size_t ws_size,
                              hipStream_t stream) {
    const float* U    = (const float*)d_in[0];  // (4096,128)
    const float* Win  = (const float*)d_in[1];  // (2048,128)
    const float* Wres = (const float*)d_in[2];  // (2048,2048)
    const float* bias = (const float*)d_in[3];  // (2048,)
    float* out = (float*)d_out;                 // (4096,2048)
    unsigned long long* slots = (unsigned long long*)d_ws;  // [NREP][2][R]

    // tag 0 / value 0 everywhere == valid x^0 = 0 in every replica's buf[0].
    hipMemsetAsync(d_ws, 0, (size_t)NREP * 2 * R * sizeof(unsigned long long),
                   stream);

    dim3 pgrid(T / 16, R / 16);
    esn_proj_kernel<<<pgrid, dim3(256), 0, stream>>>(U, Win, bias, out);

    void* args[] = { (void*)&Wres, (void*)&out, (void*)&slots };
    hipLaunchCooperativeKernel((const void*)esn_recur_kernel,
                               dim3(NWG), dim3(512), args, 0, stream);
}